// Round 6
// baseline (752.254 us; speedup 1.0000x reference)
//
#include <hip/hip_runtime.h>

#define NIN 64
#define NOUT 32
#define KK 9
#define WIN 128          // rows per window (exclusive ownership)
#define WSH 7            // log2(WIN)
#define CHUNK 1024       // pairs processed per LDS batch

typedef __attribute__((ext_vector_type(8))) short bf16x8;
typedef __attribute__((ext_vector_type(16))) float f32x16;

// fp32 -> bf16 round-to-nearest-even
__device__ __forceinline__ unsigned short f2bf_rne(float f) {
    unsigned int u = __builtin_bit_cast(unsigned int, f);
    unsigned int r = (u + 0x7FFFu + ((u >> 16) & 1u)) >> 16;
    return (unsigned short)r;
}
__device__ __forceinline__ float bf2f(unsigned short h) {
    unsigned int u = ((unsigned int)h) << 16;
    return __builtin_bit_cast(float, u);
}

// ---------------------------------------------------------------------------
// Kernel: pre-pack weights into MFMA B-fragment layout, split bf16 hi/lo.
__global__ void mink_prep_w(const float* __restrict__ w,
                            unsigned short* __restrict__ wf) {
    int t = blockIdx.x * 256 + threadIdx.x;
    if (t >= KK * 4 * 64) return;
    int l = t & 63, ks = (t >> 6) & 3, k = t >> 8;
    int col = l & 31;
    int kb = ks * 16 + (l >> 5) * 4;
    #pragma unroll
    for (int j = 0; j < 8; ++j) {
        int c = kb + (j & 3) + 8 * (j >> 2);
        float v = w[(k * NIN + c) * NOUT + col];
        unsigned short hi = f2bf_rne(v);
        unsigned short lo = f2bf_rne(v - bf2f(hi));
        wf[(size_t)((k * 4 + ks) * 64 + l) * 8 + j] = hi;
        wf[(size_t)(KK * 4 * 64 * 8) + (size_t)((k * 4 + ks) * 64 + l) * 8 + j] = lo;
    }
}

// ---------------------------------------------------------------------------
// Window-CSR build: hist -> scan -> fill. Only int atomics (~16 us total).
__global__ void mink_zero(int* __restrict__ p, int n) {
    int i = blockIdx.x * 256 + threadIdx.x;
    if (i < n) p[i] = 0;
}

__global__ void mink_hist(const int* __restrict__ oidx, int* __restrict__ hist,
                          int total) {
    int i = blockIdx.x * 256 + threadIdx.x;
    if (i < total) atomicAdd(&hist[oidx[i] >> WSH], 1);
}

// single-block exclusive scan over nwin entries; ofs==hist in place; cur copy;
// ofs[nwin] = total.
__global__ __launch_bounds__(256) void mink_scan(int* __restrict__ ofs,
                                                 int* __restrict__ cur, int nwin) {
    __shared__ int tsum[256];
    int t = threadIdx.x;
    int per = (nwin + 255) / 256;
    int base = t * per;
    int end = base + per; if (end > nwin) end = nwin;
    int s = 0;
    for (int i = base; i < end; ++i) s += ofs[i];
    tsum[t] = s;
    __syncthreads();
    if (t == 0) {
        int run = 0;
        for (int i = 0; i < 256; ++i) { int v = tsum[i]; tsum[i] = run; run += v; }
    }
    __syncthreads();
    int run = tsum[t];
    for (int i = base; i < end; ++i) {
        int v = ofs[i];
        ofs[i] = run; cur[i] = run;
        run += v;
    }
    if (t == 255) ofs[nwin] = run;
}

// rec = (n << 11) | (k << 7) | (row & 127)   [18 + 4 + 7 = 29 bits]
__global__ void mink_fill(const int* __restrict__ oidx, int* __restrict__ cur,
                          int* __restrict__ pairs, int total) {
    int i = blockIdx.x * 256 + threadIdx.x;
    if (i >= total) return;
    int n = i / KK;
    int k = i - n * KK;
    int row = oidx[i];
    int p = atomicAdd(&cur[row >> WSH], 1);
    pairs[p] = (n << 11) | (k << 7) | (row & (WIN - 1));
}

// ---------------------------------------------------------------------------
// Main kernel: one block per 128-row window. Bucket the window's pairs by k,
// MFMA (split-bf16, gathered A rows), merge via LDS fp32 atomics, write each
// output row once with fused bias+ReLU. Zero global fp atomics.
__global__ __launch_bounds__(256) void mink_gather(
    const float* __restrict__ feats,        // [N, 64] f32
    const unsigned short* __restrict__ wf,  // packed bf16 frags (hi, lo)
    const int* __restrict__ ofs,            // [nwin+1]
    const int* __restrict__ pairs,          // [9N] recs
    const float4* __restrict__ bias4,       // [8]
    float4* __restrict__ out4,              // [num_out*8]
    int num_out) {
    __shared__ float accs[(WIN + 1) * NOUT];   // +1 = dump row for pad lanes
    __shared__ int pbuf[CHUNK];
    __shared__ int kcnt[KK], kofs[KK + 1], kcur[KK], tstart[KK + 1];

    int tid  = threadIdx.x;
    int b    = blockIdx.x;
    int start = ofs[b], end = ofs[b + 1];

    for (int i = tid; i < (WIN + 1) * NOUT; i += 256) accs[i] = 0.0f;

    int lane = tid & 63;
    int wid  = tid >> 6;
    int half = lane >> 5;
    int col  = lane & 31;

    const bf16x8* wfh = (const bf16x8*)wf;
    const bf16x8* wfl = wfh + KK * 4 * 64;

    for (int cbase = start; cbase < end; cbase += CHUNK) {
        int cnt = end - cbase; if (cnt > CHUNK) cnt = CHUNK;
        if (tid < KK) kcnt[tid] = 0;
        __syncthreads();
        for (int i = tid; i < cnt; i += 256)
            atomicAdd(&kcnt[(pairs[cbase + i] >> 7) & 15], 1);
        __syncthreads();
        if (tid == 0) {
            int run = 0, trun = 0;
            #pragma unroll
            for (int k = 0; k < KK; ++k) {
                kofs[k] = run; kcur[k] = run; run += kcnt[k];
                tstart[k] = trun; trun += (kcnt[k] + 31) >> 5;
            }
            kofs[KK] = run; tstart[KK] = trun;
        }
        __syncthreads();
        for (int i = tid; i < cnt; i += 256) {
            int rec = pairs[cbase + i];
            int p = atomicAdd(&kcur[(rec >> 7) & 15], 1);
            pbuf[p] = rec;
        }
        __syncthreads();

        int ntiles = tstart[KK];
        for (int t = wid; t < ntiles; t += 4) {
            int k = 0;
            while (tstart[k + 1] <= t) ++k;     // <=9 LDS reads, wave-uniform
            int ti = t - tstart[k];
            int slot = kofs[k] + ti * 32 + col;
            int valid = slot < kofs[k] + kcnt[k];
            int rec  = valid ? pbuf[slot] : 0;
            int lrow = valid ? (rec & (WIN - 1)) : WIN;   // pad -> dump row
            int site = valid ? (rec >> 11) : 0;

            // A fragments: gathered site row -> split bf16 in-register
            const float* xrow = feats + (size_t)site * NIN;
            int kbase = half * 4;
            bf16x8 ahi[4], alo[4];
            #pragma unroll
            for (int ks = 0; ks < 4; ++ks) {
                float4 v0 = *(const float4*)(xrow + ks * 16 + kbase);
                float4 v1 = *(const float4*)(xrow + ks * 16 + kbase + 8);
                float xs[8] = {v0.x, v0.y, v0.z, v0.w, v1.x, v1.y, v1.z, v1.w};
                #pragma unroll
                for (int j = 0; j < 8; ++j) {
                    unsigned short h = f2bf_rne(xs[j]);
                    ahi[ks][j] = (short)h;
                    alo[ks][j] = (short)f2bf_rne(xs[j] - bf2f(h));
                }
            }

            f32x16 acc = {0,0,0,0,0,0,0,0,0,0,0,0,0,0,0,0};
            #pragma unroll
            for (int ks = 0; ks < 4; ++ks) {
                bf16x8 bh = wfh[(k * 4 + ks) * 64 + lane];
                bf16x8 bl = wfl[(k * 4 + ks) * 64 + lane];
                acc = __builtin_amdgcn_mfma_f32_32x32x16_bf16(ahi[ks], bh, acc, 0, 0, 0);
                acc = __builtin_amdgcn_mfma_f32_32x32x16_bf16(ahi[ks], bl, acc, 0, 0, 0);
                acc = __builtin_amdgcn_mfma_f32_32x32x16_bf16(alo[ks], bh, acc, 0, 0, 0);
            }
            // merge: C/D layout col=lane&31, tile row=(r&3)+8*(r>>2)+4*half
            #pragma unroll
            for (int r = 0; r < 16; ++r) {
                int sidx = (r & 3) + 8 * (r >> 2) + 4 * half;
                int lr = __shfl(lrow, sidx, 64);
                atomicAdd(&accs[lr * NOUT + col], acc[r]);   // ds_add_f32
            }
        }
        __syncthreads();
    }

    // write each row once: bias + ReLU fused, coalesced float4
    const float4* acc4 = (const float4*)accs;
    int base_out = b * (WIN * NOUT / 4);
    int lim = num_out * (NOUT / 4);
    for (int f = tid; f < WIN * NOUT / 4; f += 256) {
        int o = base_out + f;
        if (o < lim) {
            float4 v = acc4[f];
            float4 bb = bias4[f & 7];
            v.x = fmaxf(v.x + bb.x, 0.0f);
            v.y = fmaxf(v.y + bb.y, 0.0f);
            v.z = fmaxf(v.z + bb.z, 0.0f);
            v.w = fmaxf(v.w + bb.w, 0.0f);
            out4[o] = v;
        }
    }
}

// ---------------------------------------------------------------------------
// Fallback path (round-4, atomic scatter) in case ws_size is too small.
__global__ void mink_init_bias(float4* __restrict__ out,
                               const float4* __restrict__ bias, int n4) {
    int i = blockIdx.x * blockDim.x + threadIdx.x;
    if (i < n4) out[i] = bias[i & 7];
}

__global__ __launch_bounds__(256) void mink_scatter_mfma(
    const float* __restrict__ feats,
    const unsigned short* __restrict__ wf,
    const int* __restrict__ out_idx,
    float* __restrict__ out,
    int ntiles) {
    int wid  = (blockIdx.x * 256 + threadIdx.x) >> 6;
    int lane = threadIdx.x & 63;
    if (wid >= ntiles) return;
    int n0   = wid * 32;
    int half = lane >> 5;
    int col  = lane & 31;

    const float* xrow = feats + (size_t)(n0 + col) * NIN;
    int kbase = half * 4;
    bf16x8 ahi[4], alo[4];
    #pragma unroll
    for (int ks = 0; ks < 4; ++ks) {
        float4 v0 = *(const float4*)(xrow + ks * 16 + kbase);
        float4 v1 = *(const float4*)(xrow + ks * 16 + kbase + 8);
        float xs[8] = {v0.x, v0.y, v0.z, v0.w, v1.x, v1.y, v1.z, v1.w};
        #pragma unroll
        for (int j = 0; j < 8; ++j) {
            unsigned short h = f2bf_rne(xs[j]);
            ahi[ks][j] = (short)h;
            alo[ks][j] = (short)f2bf_rne(xs[j] - bf2f(h));
        }
    }
    const bf16x8* wfh = (const bf16x8*)wf;
    const bf16x8* wfl = wfh + KK * 4 * 64;
    #pragma unroll 1
    for (int k = 0; k < KK; ++k) {
        f32x16 acc = {0,0,0,0,0,0,0,0,0,0,0,0,0,0,0,0};
        #pragma unroll
        for (int ks = 0; ks < 4; ++ks) {
            bf16x8 bh = wfh[(k * 4 + ks) * 64 + lane];
            bf16x8 bl = wfl[(k * 4 + ks) * 64 + lane];
            acc = __builtin_amdgcn_mfma_f32_32x32x16_bf16(ahi[ks], bh, acc, 0, 0, 0);
            acc = __builtin_amdgcn_mfma_f32_32x32x16_bf16(ahi[ks], bl, acc, 0, 0, 0);
            acc = __builtin_amdgcn_mfma_f32_32x32x16_bf16(alo[ks], bh, acc, 0, 0, 0);
        }
        #pragma unroll
        for (int r = 0; r < 16; ++r) {
            int site = (r & 3) + 8 * (r >> 2) + 4 * half;
            int row = out_idx[(size_t)(n0 + site) * KK + k];
            unsafeAtomicAdd(out + (size_t)row * NOUT + col, acc[r]);
        }
    }
}

__global__ void mink_relu(float4* __restrict__ out, int n4) {
    int i = blockIdx.x * blockDim.x + threadIdx.x;
    if (i < n4) {
        float4 v = out[i];
        v.x = fmaxf(v.x, 0.0f);
        v.y = fmaxf(v.y, 0.0f);
        v.z = fmaxf(v.z, 0.0f);
        v.w = fmaxf(v.w, 0.0f);
        out[i] = v;
    }
}

extern "C" void kernel_launch(void* const* d_in, const int* in_sizes, int n_in,
                              void* d_out, int out_size, void* d_ws, size_t ws_size,
                              hipStream_t stream) {
    const float* feats  = (const float*)d_in[0];  // [N, 64] f32
    const float* weight = (const float*)d_in[1];  // [9, 64, 32] f32
    const float* bias   = (const float*)d_in[2];  // [32] f32
    const int*   oidx   = (const int*)d_in[3];    // [N, 9] i32
    float* out = (float*)d_out;                   // [num_out, 32] f32

    int n       = in_sizes[0] / NIN;              // 262144
    int n4      = out_size / 4;
    int num_out = out_size / NOUT;
    int nwin    = (num_out + WIN - 1) / WIN;
    int total   = n * KK;                          // 2,359,296 pairs

    // d_ws layout: wf | ofs[nwin+1] | cur[nwin] | pairs[total]
    unsigned short* wf = (unsigned short*)d_ws;
    size_t off = 73728;
    int* ofs   = (int*)((char*)d_ws + off);  off += (size_t)(nwin + 1) * 4;
    int* cur   = (int*)((char*)d_ws + off);  off += (size_t)nwin * 4;
    off = (off + 15) & ~(size_t)15;
    int* pairs = (int*)((char*)d_ws + off);  off += (size_t)total * 4;

    mink_prep_w<<<(KK * 4 * 64 + 255) / 256, 256, 0, stream>>>(weight, wf);

    if (off <= ws_size) {
        // ---- CSR + exclusive-window merge path (no global fp atomics)
        mink_zero<<<(nwin + 256) / 256, 256, 0, stream>>>(ofs, nwin + 1);
        mink_hist<<<(total + 255) / 256, 256, 0, stream>>>(oidx, ofs, total);
        mink_scan<<<1, 256, 0, stream>>>(ofs, cur, nwin);
        mink_fill<<<(total + 255) / 256, 256, 0, stream>>>(oidx, cur, pairs, total);
        mink_gather<<<nwin, 256, 0, stream>>>(
            feats, wf, ofs, pairs, (const float4*)bias, (float4*)out, num_out);
    } else {
        // ---- fallback: round-4 atomic scatter
        mink_init_bias<<<(n4 + 255) / 256, 256, 0, stream>>>(
            (float4*)out, (const float4*)bias, n4);
        int ntiles = n / 32;
        mink_scatter_mfma<<<ntiles * 64 / 256, 256, 0, stream>>>(
            feats, wf, oidx, out, ntiles);
        mink_relu<<<(n4 + 255) / 256, 256, 0, stream>>>((float4*)out, n4);
    }
}